// Round 1
// baseline (1221.794 us; speedup 1.0000x reference)
//
#include <hip/hip_runtime.h>
#include <hip/hip_bf16.h>
#include <stdint.h>

typedef __attribute__((ext_vector_type(8))) short bf16x8;
typedef __attribute__((ext_vector_type(4))) float f32x4;
typedef unsigned short u16;

#define M_ROWS 16384
#define N_COLS 4096
#define K_DIM  2048
#define TOPK   16
#define KCAND  24
#define INV_T  5.0f

#define BM 128
#define BN 128
#define BK 64

// ---- async global->LDS 16B copy -------------------------------------------
__device__ __forceinline__ void async_cp16(const void* g, void* l) {
  __builtin_amdgcn_global_load_lds((const __attribute__((address_space(1))) uint32_t*)g,
                                   (__attribute__((address_space(3))) uint32_t*)l,
                                   16, 0, 0);
}

__device__ __forceinline__ u16 f2bf(float f) {
  __hip_bfloat16 h = __float2bfloat16(f);
  return *reinterpret_cast<u16*>(&h);
}
__device__ __forceinline__ uint2 pack4(float4 v) {
  uint2 r;
  r.x = (uint32_t)f2bf(v.x) | ((uint32_t)f2bf(v.y) << 16);
  r.y = (uint32_t)f2bf(v.z) | ((uint32_t)f2bf(v.w) << 16);
  return r;
}

// ---- prep: per-row inv-norm of x + bf16 cast (unnormalized) ---------------
__global__ __launch_bounds__(256) void prep_x_kernel(
    const float* __restrict__ x, u16* __restrict__ xh, float* __restrict__ invn) {
  const int row = blockIdx.x;
  const int t = threadIdx.x;
  const float4* xr = reinterpret_cast<const float4*>(x + (size_t)row * K_DIM);
  float4 v0 = xr[t];
  float4 v1 = xr[256 + t];
  float s = v0.x*v0.x + v0.y*v0.y + v0.z*v0.z + v0.w*v0.w
          + v1.x*v1.x + v1.y*v1.y + v1.z*v1.z + v1.w*v1.w;
  #pragma unroll
  for (int off = 1; off < 64; off <<= 1) s += __shfl_xor(s, off);
  __shared__ float ws4[4];
  if ((t & 63) == 0) ws4[t >> 6] = s;
  __syncthreads();
  if (t == 0) {
    float tot = ws4[0] + ws4[1] + ws4[2] + ws4[3];
    invn[row] = 1.0f / fmaxf(sqrtf(tot), 1e-12f);
  }
  uint2* xo = reinterpret_cast<uint2*>(xh + (size_t)row * K_DIM);
  xo[t] = pack4(v0);
  xo[256 + t] = pack4(v1);
}

// ---- prep: protos fp32 -> bf16 --------------------------------------------
__global__ __launch_bounds__(256) void prep_p_kernel(
    const float* __restrict__ p, u16* __restrict__ ph) {
  const int row = blockIdx.x;
  const int t = threadIdx.x;
  const float4* pr = reinterpret_cast<const float4*>(p + (size_t)row * K_DIM);
  uint2* po = reinterpret_cast<uint2*>(ph + (size_t)row * K_DIM);
  po[t] = pack4(pr[t]);
  po[256 + t] = pack4(pr[256 + t]);
}

// ---- bf16 GEMM: sims[m][n] = sum_k A[m][k]*B[n][k]  (B^T layout) ----------
// 128x128 tile, BK=64, 4 waves (2x2), each wave 64x64 = 4x4 frags of 16x16x32.
// LDS XOR-swizzle (byte ^= (row&7)<<4) applied on the *global source* address
// (global_load_lds writes linearly) and on the ds_read address.
__global__ __launch_bounds__(256) void gemm_bf16_kernel(
    const u16* __restrict__ A, const u16* __restrict__ B, float* __restrict__ C) {
  __shared__ __align__(16) u16 sA[BM * BK];
  __shared__ __align__(16) u16 sB[BN * BK];
  const int t = threadIdx.x;
  const int lane = t & 63;
  const int wid = t >> 6;
  const int wm = wid >> 1, wn = wid & 1;
  const int tm0 = blockIdx.y * BM;
  const int tn0 = blockIdx.x * BN;

  f32x4 acc[4][4];
  #pragma unroll
  for (int i = 0; i < 4; ++i)
    #pragma unroll
    for (int j = 0; j < 4; ++j)
      acc[i][j] = (f32x4){0.f, 0.f, 0.f, 0.f};

  // staging source offsets (swizzled) for 4 chunks each of A and B
  int srow[4], soff[4];
  #pragma unroll
  for (int i = 0; i < 4; ++i) {
    int c = i * 256 + t;
    int r = c >> 3;
    int ib = (c & 7) << 4;
    srow[i] = r;
    soff[i] = ib ^ ((r & 7) << 4);
  }
  const char* Abase = (const char*)(A + (size_t)tm0 * K_DIM);
  const char* Bbase = (const char*)(B + (size_t)tn0 * K_DIM);

  const int lr = lane & 15;
  const int hi = lane >> 4;

  for (int kt = 0; kt < K_DIM / BK; ++kt) {
    const int kbyte = kt * (BK * 2);
    #pragma unroll
    for (int i = 0; i < 4; ++i) {
      async_cp16(Abase + (size_t)srow[i] * (K_DIM * 2) + kbyte + soff[i],
                 (char*)sA + (i * 256 + t) * 16);
      async_cp16(Bbase + (size_t)srow[i] * (K_DIM * 2) + kbyte + soff[i],
                 (char*)sB + (i * 256 + t) * 16);
    }
    __syncthreads();   // compiler drains vmcnt before s_barrier
    #pragma unroll
    for (int kk = 0; kk < 2; ++kk) {
      bf16x8 af[4], bfr[4];
      #pragma unroll
      for (int f = 0; f < 4; ++f) {
        int rowA = wm * 64 + f * 16 + lr;
        int inbA = (kk * 64 + (hi << 4)) ^ ((rowA & 7) << 4);
        af[f] = *reinterpret_cast<const bf16x8*>((const char*)sA + rowA * 128 + inbA);
        int rowB = wn * 64 + f * 16 + lr;
        int inbB = (kk * 64 + (hi << 4)) ^ ((rowB & 7) << 4);
        bfr[f] = *reinterpret_cast<const bf16x8*>((const char*)sB + rowB * 128 + inbB);
      }
      #pragma unroll
      for (int i = 0; i < 4; ++i)
        #pragma unroll
        for (int j = 0; j < 4; ++j)
          acc[i][j] = __builtin_amdgcn_mfma_f32_16x16x32_bf16(af[i], bfr[j], acc[i][j], 0, 0, 0);
    }
    __syncthreads();
  }

  // C write: col = lane&15, row = (lane>>4)*4 + reg  (m89-verified layout)
  #pragma unroll
  for (int i = 0; i < 4; ++i) {
    #pragma unroll
    for (int j = 0; j < 4; ++j) {
      int colg = tn0 + wn * 64 + j * 16 + lr;
      int rowb = tm0 + wm * 64 + i * 16 + (hi << 2);
      #pragma unroll
      for (int r = 0; r < 4; ++r) {
        C[(size_t)(rowb + r) * N_COLS + colg] = acc[i][j][r];
      }
    }
  }
}

// ---- per-row: top-KCAND approx -> exact fp32 rescore -> top-16 softmax ----
__global__ __launch_bounds__(256) void topk_kernel(
    const float* __restrict__ x, const float* __restrict__ protos,
    const float* __restrict__ invn, float* __restrict__ out) {
  const int row = blockIdx.x;
  const int t = threadIdx.x;
  const int lane = t & 63;
  const int wid = t >> 6;

  __shared__ __align__(16) float4 lx[512];      // x row, 8 KB
  __shared__ __align__(16) float img[N_COLS];   // output row image, 16 KB
  __shared__ int   cand[KCAND];
  __shared__ float cexact[KCAND];
  __shared__ float wv[4];
  __shared__ int   wi[4];
  __shared__ int   bci;

  float* orow = out + (size_t)row * N_COLS;
  const float4* orow4 = reinterpret_cast<const float4*>(orow);

  // load approx sims into registers (16 floats/thread, lane-coalesced)
  float4 sv[4];
  #pragma unroll
  for (int i = 0; i < 4; ++i) sv[i] = orow4[i * 256 + t];

  // stage x row into LDS
  const float4* xr = reinterpret_cast<const float4*>(x + (size_t)row * K_DIM);
  lx[t] = xr[t];
  lx[256 + t] = xr[256 + t];

  // zero output image
  float4 z4 = {0.f, 0.f, 0.f, 0.f};
  float4* img4 = reinterpret_cast<float4*>(img);
  #pragma unroll
  for (int i = 0; i < 4; ++i) img4[i * 256 + t] = z4;

  // --- iterative top-KCAND selection on approx sims ---
  unsigned mask = 0;
  for (int it = 0; it < KCAND; ++it) {
    float bv = -3.0e38f;
    int bi = 0x7fffffff;
    #pragma unroll
    for (int i = 0; i < 4; ++i) {
      #pragma unroll
      for (int c = 0; c < 4; ++c) {
        int j = i * 4 + c;
        float v = ((const float*)&sv[i])[c];
        int gidx = i * 1024 + t * 4 + c;
        bool ok = !((mask >> j) & 1);
        if (ok && (v > bv || (v == bv && gidx < bi))) { bv = v; bi = gidx; }
      }
    }
    #pragma unroll
    for (int off = 1; off < 64; off <<= 1) {
      float ov = __shfl_xor(bv, off);
      int   oi = __shfl_xor(bi, off);
      if (ov > bv || (ov == bv && oi < bi)) { bv = ov; bi = oi; }
    }
    if (lane == 0) { wv[wid] = bv; wi[wid] = bi; }
    __syncthreads();
    if (t == 0) {
      float fv = wv[0]; int fi = wi[0];
      for (int w2 = 1; w2 < 4; ++w2)
        if (wv[w2] > fv || (wv[w2] == fv && wi[w2] < fi)) { fv = wv[w2]; fi = wi[w2]; }
      cand[it] = fi;
      bci = fi;
    }
    __syncthreads();
    int fi = bci;
    if (((fi >> 2) & 255) == t) mask |= 1u << (((fi >> 10) << 2) | (fi & 3));
  }
  __syncthreads();

  // --- exact fp32 rescore of the KCAND candidates ---
  const float inv = invn[row];
  #pragma unroll
  for (int q = 0; q < KCAND / 4; ++q) {
    int ci = wid * (KCAND / 4) + q;
    int pidx = cand[ci];
    const float4* pr = reinterpret_cast<const float4*>(protos + (size_t)pidx * K_DIM);
    float s = 0.f;
    #pragma unroll
    for (int i = 0; i < 8; ++i) {
      float4 pv = pr[i * 64 + lane];
      float4 xv = lx[i * 64 + lane];
      s = fmaf(pv.x, xv.x, s);
      s = fmaf(pv.y, xv.y, s);
      s = fmaf(pv.z, xv.z, s);
      s = fmaf(pv.w, xv.w, s);
    }
    #pragma unroll
    for (int off = 1; off < 64; off <<= 1) s += __shfl_xor(s, off);
    if (lane == 0) cexact[ci] = s * inv;
  }
  __syncthreads();

  // --- exact top-16 of KCAND + softmax + scatter (wave 0) ---
  if (wid == 0) {
    float v = (lane < KCAND) ? cexact[lane] : -3.0e38f;
    int pos = (lane < KCAND) ? cand[lane] : 0x7fffffff;
    int rank = 0;
    for (int j = 0; j < KCAND; ++j) {
      float vj = __shfl(v, j);
      int   pj = __shfl(pos, j);
      if (lane < KCAND && j != lane)
        if (vj > v || (vj == v && pj < pos)) rank++;
    }
    bool sel = (lane < KCAND) && (rank < TOPK);
    float vm = sel ? v : -3.0e38f;
    #pragma unroll
    for (int off = 1; off < 64; off <<= 1) vm = fmaxf(vm, __shfl_xor(vm, off));
    float e = sel ? expf((v - vm) * INV_T) : 0.f;
    float se = e;
    #pragma unroll
    for (int off = 1; off < 64; off <<= 1) se += __shfl_xor(se, off);
    if (sel) img[pos] = e / se;
  }
  __syncthreads();

  // write the full row back (zeros + 16 softmax values)
  float4* orow4w = reinterpret_cast<float4*>(orow);
  #pragma unroll
  for (int i = 0; i < 4; ++i) orow4w[i * 256 + t] = img4[i * 256 + t];
}

extern "C" void kernel_launch(void* const* d_in, const int* in_sizes, int n_in,
                              void* d_out, int out_size, void* d_ws, size_t ws_size,
                              hipStream_t stream) {
  const float* x = (const float*)d_in[0];
  const float* protos = (const float*)d_in[1];
  float* out = (float*)d_out;

  char* ws = (char*)d_ws;
  u16* xh = (u16*)ws;                                        // 64 MB
  u16* ph = (u16*)(ws + (size_t)M_ROWS * K_DIM * 2);         // 16 MB
  float* invn = (float*)(ws + (size_t)(M_ROWS + N_COLS) * K_DIM * 2); // 64 KB

  prep_x_kernel<<<M_ROWS, 256, 0, stream>>>(x, xh, invn);
  prep_p_kernel<<<N_COLS, 256, 0, stream>>>(protos, ph);

  dim3 gg(N_COLS / BN, M_ROWS / BM);
  gemm_bf16_kernel<<<gg, 256, 0, stream>>>(xh, ph, out);

  topk_kernel<<<M_ROWS, 256, 0, stream>>>(x, protos, invn, out);
}

// Round 2
// 898.029 us; speedup vs baseline: 1.3605x; 1.3605x over previous
//
#include <hip/hip_runtime.h>
#include <hip/hip_bf16.h>
#include <stdint.h>

typedef __attribute__((ext_vector_type(8))) short bf16x8;
typedef __attribute__((ext_vector_type(4))) float f32x4;
typedef unsigned short u16;

#define M_ROWS 16384
#define N_COLS 4096
#define K_DIM  2048
#define TOPK   16
#define KSEL   24
#define CAP    32
#define INV_T  5.0f

#define BM 128
#define BN 128
#define BK 64

// ---- async global->LDS 16B copy -------------------------------------------
__device__ __forceinline__ void async_cp16(const void* g, void* l) {
  __builtin_amdgcn_global_load_lds((const __attribute__((address_space(1))) uint32_t*)g,
                                   (__attribute__((address_space(3))) uint32_t*)l,
                                   16, 0, 0);
}

__device__ __forceinline__ u16 f2bf(float f) {
  __hip_bfloat16 h = __float2bfloat16(f);
  return *reinterpret_cast<u16*>(&h);
}
__device__ __forceinline__ uint2 pack4(float4 v) {
  uint2 r;
  r.x = (uint32_t)f2bf(v.x) | ((uint32_t)f2bf(v.y) << 16);
  r.y = (uint32_t)f2bf(v.z) | ((uint32_t)f2bf(v.w) << 16);
  return r;
}

// ---- prep: per-row inv-norm of x + bf16 cast (unnormalized) ---------------
__global__ __launch_bounds__(256) void prep_x_kernel(
    const float* __restrict__ x, u16* __restrict__ xh, float* __restrict__ invn) {
  const int row = blockIdx.x;
  const int t = threadIdx.x;
  const float4* xr = reinterpret_cast<const float4*>(x + (size_t)row * K_DIM);
  float4 v0 = xr[t];
  float4 v1 = xr[256 + t];
  float s = v0.x*v0.x + v0.y*v0.y + v0.z*v0.z + v0.w*v0.w
          + v1.x*v1.x + v1.y*v1.y + v1.z*v1.z + v1.w*v1.w;
  #pragma unroll
  for (int off = 1; off < 64; off <<= 1) s += __shfl_xor(s, off);
  __shared__ float ws4[4];
  if ((t & 63) == 0) ws4[t >> 6] = s;
  __syncthreads();
  if (t == 0) {
    float tot = ws4[0] + ws4[1] + ws4[2] + ws4[3];
    invn[row] = 1.0f / fmaxf(sqrtf(tot), 1e-12f);
  }
  uint2* xo = reinterpret_cast<uint2*>(xh + (size_t)row * K_DIM);
  xo[t] = pack4(v0);
  xo[256 + t] = pack4(v1);
}

// ---- prep: protos fp32 -> bf16 --------------------------------------------
__global__ __launch_bounds__(256) void prep_p_kernel(
    const float* __restrict__ p, u16* __restrict__ ph) {
  const int row = blockIdx.x;
  const int t = threadIdx.x;
  const float4* pr = reinterpret_cast<const float4*>(p + (size_t)row * K_DIM);
  uint2* po = reinterpret_cast<uint2*>(ph + (size_t)row * K_DIM);
  po[t] = pack4(pr[t]);
  po[256 + t] = pack4(pr[256 + t]);
}

// ---- bf16 GEMM: sims[m][n] = sum_k A[m][k]*B[n][k]  (B^T layout) ----------
__global__ __launch_bounds__(256) void gemm_bf16_kernel(
    const u16* __restrict__ A, const u16* __restrict__ B, float* __restrict__ C) {
  __shared__ __align__(16) u16 sA[BM * BK];
  __shared__ __align__(16) u16 sB[BN * BK];
  const int t = threadIdx.x;
  const int lane = t & 63;
  const int wid = t >> 6;
  const int wm = wid >> 1, wn = wid & 1;
  const int tm0 = blockIdx.y * BM;
  const int tn0 = blockIdx.x * BN;

  f32x4 acc[4][4];
  #pragma unroll
  for (int i = 0; i < 4; ++i)
    #pragma unroll
    for (int j = 0; j < 4; ++j)
      acc[i][j] = (f32x4){0.f, 0.f, 0.f, 0.f};

  int srow[4], soff[4];
  #pragma unroll
  for (int i = 0; i < 4; ++i) {
    int c = i * 256 + t;
    int r = c >> 3;
    int ib = (c & 7) << 4;
    srow[i] = r;
    soff[i] = ib ^ ((r & 7) << 4);
  }
  const char* Abase = (const char*)(A + (size_t)tm0 * K_DIM);
  const char* Bbase = (const char*)(B + (size_t)tn0 * K_DIM);

  const int lr = lane & 15;
  const int hi = lane >> 4;

  for (int kt = 0; kt < K_DIM / BK; ++kt) {
    const int kbyte = kt * (BK * 2);
    #pragma unroll
    for (int i = 0; i < 4; ++i) {
      async_cp16(Abase + (size_t)srow[i] * (K_DIM * 2) + kbyte + soff[i],
                 (char*)sA + (i * 256 + t) * 16);
      async_cp16(Bbase + (size_t)srow[i] * (K_DIM * 2) + kbyte + soff[i],
                 (char*)sB + (i * 256 + t) * 16);
    }
    __syncthreads();
    #pragma unroll
    for (int kk = 0; kk < 2; ++kk) {
      bf16x8 af[4], bfr[4];
      #pragma unroll
      for (int f = 0; f < 4; ++f) {
        int rowA = wm * 64 + f * 16 + lr;
        int inbA = (kk * 64 + (hi << 4)) ^ ((rowA & 7) << 4);
        af[f] = *reinterpret_cast<const bf16x8*>((const char*)sA + rowA * 128 + inbA);
        int rowB = wn * 64 + f * 16 + lr;
        int inbB = (kk * 64 + (hi << 4)) ^ ((rowB & 7) << 4);
        bfr[f] = *reinterpret_cast<const bf16x8*>((const char*)sB + rowB * 128 + inbB);
      }
      #pragma unroll
      for (int i = 0; i < 4; ++i)
        #pragma unroll
        for (int j = 0; j < 4; ++j)
          acc[i][j] = __builtin_amdgcn_mfma_f32_16x16x32_bf16(af[i], bfr[j], acc[i][j], 0, 0, 0);
    }
    __syncthreads();
  }

  #pragma unroll
  for (int i = 0; i < 4; ++i) {
    #pragma unroll
    for (int j = 0; j < 4; ++j) {
      int colg = tn0 + wn * 64 + j * 16 + lr;
      int rowb = tm0 + wm * 64 + i * 16 + (hi << 2);
      #pragma unroll
      for (int r = 0; r < 4; ++r) {
        C[(size_t)(rowb + r) * N_COLS + colg] = acc[i][j][r];
      }
    }
  }
}

// ---- per-row: radix-select top-KSEL approx -> exact fp32 rescore -> top-16
__global__ __launch_bounds__(256) void topk_kernel(
    const float* __restrict__ x, const float* __restrict__ protos,
    const float* __restrict__ invn, float* __restrict__ out) {
  const int row = blockIdx.x;
  const int t = threadIdx.x;
  const int lane = t & 63;
  const int wid = t >> 6;

  __shared__ __align__(16) float4 lx[512];      // x row, 8 KB
  __shared__ __align__(16) float img[N_COLS];   // output row image, 16 KB
  __shared__ int hist[4][256];                  // per-wave histogram copies, 4 KB
  __shared__ int selInfo[2];                    // {selected byte, new K_rem}
  __shared__ int   cand[CAP];
  __shared__ float cexact[CAP];
  __shared__ int cnt;

  float* orow = out + (size_t)row * N_COLS;
  const float4* orow4 = reinterpret_cast<const float4*>(orow);

  // load approx sims (16 floats/thread, coalesced) + order-preserving keys
  float4 sv[4];
  #pragma unroll
  for (int i = 0; i < 4; ++i) sv[i] = orow4[i * 256 + t];
  uint32_t key[16];
  #pragma unroll
  for (int i = 0; i < 4; ++i) {
    #pragma unroll
    for (int c = 0; c < 4; ++c) {
      uint32_t u = __float_as_uint(((const float*)&sv[i])[c]);
      key[i * 4 + c] = (u & 0x80000000u) ? ~u : (u | 0x80000000u);
    }
  }

  // stage x row into LDS
  const float4* xr = reinterpret_cast<const float4*>(x + (size_t)row * K_DIM);
  lx[t] = xr[t];
  lx[256 + t] = xr[256 + t];

  // zero output image
  float4 z4 = {0.f, 0.f, 0.f, 0.f};
  float4* img4 = reinterpret_cast<float4*>(img);
  #pragma unroll
  for (int i = 0; i < 4; ++i) img4[i * 256 + t] = z4;
  if (t == 0) cnt = 0;

  // --- 4-pass radix select: exact KSEL-th largest key -> threshold T ---
  uint32_t prefix = 0;
  int K_rem = KSEL;
  #pragma unroll
  for (int pass = 0; pass < 4; ++pass) {
    const int shift = 24 - pass * 8;
    hist[0][t] = 0; hist[1][t] = 0; hist[2][t] = 0; hist[3][t] = 0;
    __syncthreads();
    const uint32_t prefMask = (pass == 0) ? 0u : (0xFFFFFFFFu << (shift + 8));
    #pragma unroll
    for (int j = 0; j < 16; ++j) {
      if ((key[j] & prefMask) == prefix)
        atomicAdd(&hist[wid][(key[j] >> shift) & 255], 1);
    }
    __syncthreads();
    if (wid == 0) {
      const int b0 = lane << 2;
      int h0 = hist[0][b0]     + hist[1][b0]     + hist[2][b0]     + hist[3][b0];
      int h1 = hist[0][b0 + 1] + hist[1][b0 + 1] + hist[2][b0 + 1] + hist[3][b0 + 1];
      int h2 = hist[0][b0 + 2] + hist[1][b0 + 2] + hist[2][b0 + 2] + hist[3][b0 + 2];
      int h3 = hist[0][b0 + 3] + hist[1][b0 + 3] + hist[2][b0 + 3] + hist[3][b0 + 3];
      int loc = h0 + h1 + h2 + h3;
      // inclusive suffix scan across lanes
      int s = loc;
      #pragma unroll
      for (int off = 1; off < 64; off <<= 1) {
        int o = __shfl_down(s, off);
        if (lane + off < 64) s += o;
      }
      const int tail = s - loc;   // sum over lanes > lane
      int s3 = tail + h3;
      int s2 = s3 + h2;
      int s1 = s2 + h1;
      int s0 = s1 + h0;
      int ge[4] = {s0, s1, s2, s3};
      int hh[4] = {h0, h1, h2, h3};
      #pragma unroll
      for (int k = 0; k < 4; ++k) {
        int gt = ge[k] - hh[k];
        if (gt < K_rem && ge[k] >= K_rem) {
          selInfo[0] = b0 + k;
          selInfo[1] = K_rem - gt;
        }
      }
    }
    __syncthreads();
    prefix |= ((uint32_t)selInfo[0]) << shift;
    K_rem = selInfo[1];
  }
  const uint32_t T = prefix;

  // --- compact candidates: all keys > T, then ties == T (cap CAP) ---
  #pragma unroll
  for (int j = 0; j < 16; ++j) {
    if (key[j] > T) {
      int s = atomicAdd(&cnt, 1);
      cand[s] = ((j >> 2) << 10) + (t << 2) + (j & 3);
    }
  }
  __syncthreads();
  #pragma unroll
  for (int j = 0; j < 16; ++j) {
    if (key[j] == T) {
      int s = atomicAdd(&cnt, 1);
      if (s < CAP) cand[s] = ((j >> 2) << 10) + (t << 2) + (j & 3);
    }
  }
  __syncthreads();
  const int c = min(cnt, CAP);

  // --- exact fp32 rescore (arithmetic order identical to R1) ---
  const float inv = invn[row];
  for (int ci = wid; ci < c; ci += 4) {
    int pidx = cand[ci];
    const float4* pr = reinterpret_cast<const float4*>(protos + (size_t)pidx * K_DIM);
    float s = 0.f;
    #pragma unroll
    for (int i = 0; i < 8; ++i) {
      float4 pv = pr[i * 64 + lane];
      float4 xv = lx[i * 64 + lane];
      s = fmaf(pv.x, xv.x, s);
      s = fmaf(pv.y, xv.y, s);
      s = fmaf(pv.z, xv.z, s);
      s = fmaf(pv.w, xv.w, s);
    }
    #pragma unroll
    for (int off = 1; off < 64; off <<= 1) s += __shfl_xor(s, off);
    if (lane == 0) cexact[ci] = s * inv;
  }
  __syncthreads();

  // --- exact top-16 of c candidates + softmax + scatter (wave 0) ---
  if (wid == 0) {
    float v = (lane < c) ? cexact[lane] : -3.0e38f;
    int pos = (lane < c) ? cand[lane] : 0x7fffffff;
    int rank = 0;
    for (int j = 0; j < c; ++j) {
      float vj = __shfl(v, j);
      int   pj = __shfl(pos, j);
      if (lane < c && j != lane)
        if (vj > v || (vj == v && pj < pos)) rank++;
    }
    bool sel = (lane < c) && (rank < TOPK);
    float vm = sel ? v : -3.0e38f;
    #pragma unroll
    for (int off = 1; off < 64; off <<= 1) vm = fmaxf(vm, __shfl_xor(vm, off));
    float e = sel ? expf((v - vm) * INV_T) : 0.f;
    float se = e;
    #pragma unroll
    for (int off = 1; off < 64; off <<= 1) se += __shfl_xor(se, off);
    if (sel) img[pos] = e / se;
  }
  __syncthreads();

  // write the full row back (zeros + 16 softmax values)
  float4* orow4w = reinterpret_cast<float4*>(orow);
  #pragma unroll
  for (int i = 0; i < 4; ++i) orow4w[i * 256 + t] = img4[i * 256 + t];
}

extern "C" void kernel_launch(void* const* d_in, const int* in_sizes, int n_in,
                              void* d_out, int out_size, void* d_ws, size_t ws_size,
                              hipStream_t stream) {
  const float* x = (const float*)d_in[0];
  const float* protos = (const float*)d_in[1];
  float* out = (float*)d_out;

  char* ws = (char*)d_ws;
  u16* xh = (u16*)ws;                                        // 64 MB
  u16* ph = (u16*)(ws + (size_t)M_ROWS * K_DIM * 2);         // 16 MB
  float* invn = (float*)(ws + (size_t)(M_ROWS + N_COLS) * K_DIM * 2); // 64 KB

  prep_x_kernel<<<M_ROWS, 256, 0, stream>>>(x, xh, invn);
  prep_p_kernel<<<N_COLS, 256, 0, stream>>>(protos, ph);

  dim3 gg(N_COLS / BN, M_ROWS / BM);
  gemm_bf16_kernel<<<gg, 256, 0, stream>>>(xh, ph, out);

  topk_kernel<<<M_ROWS, 256, 0, stream>>>(x, protos, invn, out);
}

// Round 4
// 818.036 us; speedup vs baseline: 1.4936x; 1.0978x over previous
//
#include <hip/hip_runtime.h>
#include <hip/hip_bf16.h>
#include <stdint.h>

typedef __attribute__((ext_vector_type(8))) short bf16x8;
typedef __attribute__((ext_vector_type(4))) float f32x4;
typedef unsigned short u16;

#define M_ROWS 16384
#define N_COLS 4096
#define K_DIM  2048
#define TOPK   16
#define KSEL   24
#define CAP    32
#define INV_T  5.0f

#define BM 128
#define BN 128
#define BK 64

// ---- async global->LDS 16B copy -------------------------------------------
__device__ __forceinline__ void async_cp16(const void* g, void* l) {
  __builtin_amdgcn_global_load_lds((const __attribute__((address_space(1))) uint32_t*)g,
                                   (__attribute__((address_space(3))) uint32_t*)l,
                                   16, 0, 0);
}

__device__ __forceinline__ u16 f2bf(float f) {
  __hip_bfloat16 h = __float2bfloat16(f);
  return *reinterpret_cast<u16*>(&h);
}
__device__ __forceinline__ uint2 pack4(float4 v) {
  uint2 r;
  r.x = (uint32_t)f2bf(v.x) | ((uint32_t)f2bf(v.y) << 16);
  r.y = (uint32_t)f2bf(v.z) | ((uint32_t)f2bf(v.w) << 16);
  return r;
}

// ---- prep: per-row inv-norm of x + bf16 cast (unnormalized) ---------------
__global__ __launch_bounds__(256) void prep_x_kernel(
    const float* __restrict__ x, u16* __restrict__ xh, float* __restrict__ invn) {
  const int row = blockIdx.x;
  const int t = threadIdx.x;
  const float4* xr = reinterpret_cast<const float4*>(x + (size_t)row * K_DIM);
  float4 v0 = xr[t];
  float4 v1 = xr[256 + t];
  float s = v0.x*v0.x + v0.y*v0.y + v0.z*v0.z + v0.w*v0.w
          + v1.x*v1.x + v1.y*v1.y + v1.z*v1.z + v1.w*v1.w;
  #pragma unroll
  for (int off = 1; off < 64; off <<= 1) s += __shfl_xor(s, off);
  __shared__ float ws4[4];
  if ((t & 63) == 0) ws4[t >> 6] = s;
  __syncthreads();
  if (t == 0) {
    float tot = ws4[0] + ws4[1] + ws4[2] + ws4[3];
    invn[row] = 1.0f / fmaxf(sqrtf(tot), 1e-12f);
  }
  uint2* xo = reinterpret_cast<uint2*>(xh + (size_t)row * K_DIM);
  xo[t] = pack4(v0);
  xo[256 + t] = pack4(v1);
}

// ---- prep: protos fp32 -> bf16 --------------------------------------------
__global__ __launch_bounds__(256) void prep_p_kernel(
    const float* __restrict__ p, u16* __restrict__ ph) {
  const int row = blockIdx.x;
  const int t = threadIdx.x;
  const float4* pr = reinterpret_cast<const float4*>(p + (size_t)row * K_DIM);
  uint2* po = reinterpret_cast<uint2*>(ph + (size_t)row * K_DIM);
  po[t] = pack4(pr[t]);
  po[256 + t] = pack4(pr[256 + t]);
}

// ---- bf16 GEMM: sims[m][n] = sum_k A[m][k]*B[n][k]  (B^T layout) ----------
__global__ __launch_bounds__(256) void gemm_bf16_kernel(
    const u16* __restrict__ A, const u16* __restrict__ B, float* __restrict__ C) {
  __shared__ __align__(16) u16 sA[BM * BK];
  __shared__ __align__(16) u16 sB[BN * BK];
  const int t = threadIdx.x;
  const int lane = t & 63;
  const int wid = t >> 6;
  const int wm = wid >> 1, wn = wid & 1;
  const int tm0 = blockIdx.y * BM;
  const int tn0 = blockIdx.x * BN;

  f32x4 acc[4][4];
  #pragma unroll
  for (int i = 0; i < 4; ++i)
    #pragma unroll
    for (int j = 0; j < 4; ++j)
      acc[i][j] = (f32x4){0.f, 0.f, 0.f, 0.f};

  int srow[4], soff[4];
  #pragma unroll
  for (int i = 0; i < 4; ++i) {
    int c = i * 256 + t;
    int r = c >> 3;
    int ib = (c & 7) << 4;
    srow[i] = r;
    soff[i] = ib ^ ((r & 7) << 4);
  }
  const char* Abase = (const char*)(A + (size_t)tm0 * K_DIM);
  const char* Bbase = (const char*)(B + (size_t)tn0 * K_DIM);

  const int lr = lane & 15;
  const int hi = lane >> 4;

  for (int kt = 0; kt < K_DIM / BK; ++kt) {
    const int kbyte = kt * (BK * 2);
    #pragma unroll
    for (int i = 0; i < 4; ++i) {
      async_cp16(Abase + (size_t)srow[i] * (K_DIM * 2) + kbyte + soff[i],
                 (char*)sA + (i * 256 + t) * 16);
      async_cp16(Bbase + (size_t)srow[i] * (K_DIM * 2) + kbyte + soff[i],
                 (char*)sB + (i * 256 + t) * 16);
    }
    __syncthreads();
    #pragma unroll
    for (int kk = 0; kk < 2; ++kk) {
      bf16x8 af[4], bfr[4];
      #pragma unroll
      for (int f = 0; f < 4; ++f) {
        int rowA = wm * 64 + f * 16 + lr;
        int inbA = (kk * 64 + (hi << 4)) ^ ((rowA & 7) << 4);
        af[f] = *reinterpret_cast<const bf16x8*>((const char*)sA + rowA * 128 + inbA);
        int rowB = wn * 64 + f * 16 + lr;
        int inbB = (kk * 64 + (hi << 4)) ^ ((rowB & 7) << 4);
        bfr[f] = *reinterpret_cast<const bf16x8*>((const char*)sB + rowB * 128 + inbB);
      }
      #pragma unroll
      for (int i = 0; i < 4; ++i)
        #pragma unroll
        for (int j = 0; j < 4; ++j)
          acc[i][j] = __builtin_amdgcn_mfma_f32_16x16x32_bf16(af[i], bfr[j], acc[i][j], 0, 0, 0);
    }
    __syncthreads();
  }

  #pragma unroll
  for (int i = 0; i < 4; ++i) {
    #pragma unroll
    for (int j = 0; j < 4; ++j) {
      int colg = tn0 + wn * 64 + j * 16 + lr;
      int rowb = tm0 + wm * 64 + i * 16 + (hi << 2);
      #pragma unroll
      for (int r = 0; r < 4; ++r) {
        __builtin_nontemporal_store(acc[i][j][r], &C[(size_t)(rowb + r) * N_COLS + colg]);
      }
    }
  }
}

// ---- per-row: 4-pass 32-bit radix select (R2-proven) -> exact rescore -> top-16
__global__ __launch_bounds__(256) void topk_kernel(
    const float* __restrict__ x, const float* __restrict__ protos,
    const float* __restrict__ invn, float* __restrict__ out) {
  const int row = blockIdx.x;
  const int t = threadIdx.x;
  const int lane = t & 63;
  const int wid = t >> 6;

  __shared__ __align__(16) f32x4 lx[512];       // x row, 8 KB
  __shared__ int hist[4][257];                  // padded -> distinct banks
  __shared__ int selInfo[2];
  __shared__ int   cand[CAP];
  __shared__ float cexact[CAP];
  __shared__ int   spos[TOPK];
  __shared__ float sval[TOPK];
  __shared__ int cnt, csel;

  float* orow = out + (size_t)row * N_COLS;
  const f32x4* orow4 = reinterpret_cast<const f32x4*>(orow);

  // load approx sims (nt, streaming) -> 32-bit order-preserving keys
  uint32_t key[16];
  #pragma unroll
  for (int i = 0; i < 4; ++i) {
    f32x4 v = __builtin_nontemporal_load(orow4 + i * 256 + t);
    #pragma unroll
    for (int c = 0; c < 4; ++c) {
      uint32_t u = __float_as_uint(v[c]);
      key[i * 4 + c] = (u & 0x80000000u) ? ~u : (u | 0x80000000u);
    }
  }

  // stage x row into LDS (nt, streaming)
  const f32x4* xr = reinterpret_cast<const f32x4*>(x + (size_t)row * K_DIM);
  lx[t] = __builtin_nontemporal_load(xr + t);
  lx[256 + t] = __builtin_nontemporal_load(xr + 256 + t);
  if (t == 0) cnt = 0;

  // --- 4-pass radix select: exact KSEL-th largest 32-bit key (R2 verbatim) ---
  uint32_t prefix = 0;
  int K_rem = KSEL;
  #pragma unroll
  for (int pass = 0; pass < 4; ++pass) {
    const int shift = 24 - pass * 8;
    hist[0][t] = 0; hist[1][t] = 0; hist[2][t] = 0; hist[3][t] = 0;
    __syncthreads();
    const uint32_t prefMask = (pass == 0) ? 0u : (0xFFFFFFFFu << (shift + 8));
    #pragma unroll
    for (int j = 0; j < 16; ++j) {
      if ((key[j] & prefMask) == prefix)
        atomicAdd(&hist[wid][(key[j] >> shift) & 255], 1);
    }
    __syncthreads();
    if (wid == 0) {
      const int b0 = lane << 2;
      int h0 = hist[0][b0]     + hist[1][b0]     + hist[2][b0]     + hist[3][b0];
      int h1 = hist[0][b0 + 1] + hist[1][b0 + 1] + hist[2][b0 + 1] + hist[3][b0 + 1];
      int h2 = hist[0][b0 + 2] + hist[1][b0 + 2] + hist[2][b0 + 2] + hist[3][b0 + 2];
      int h3 = hist[0][b0 + 3] + hist[1][b0 + 3] + hist[2][b0 + 3] + hist[3][b0 + 3];
      int loc = h0 + h1 + h2 + h3;
      int s = loc;
      #pragma unroll
      for (int off = 1; off < 64; off <<= 1) {
        int o = __shfl_down(s, off);
        if (lane + off < 64) s += o;
      }
      const int tail = s - loc;
      int s3 = tail + h3;
      int s2 = s3 + h2;
      int s1 = s2 + h1;
      int s0 = s1 + h0;
      int ge[4] = {s0, s1, s2, s3};
      int hh[4] = {h0, h1, h2, h3};
      #pragma unroll
      for (int k = 0; k < 4; ++k) {
        int gt = ge[k] - hh[k];
        if (gt < K_rem && ge[k] >= K_rem) {
          selInfo[0] = b0 + k;
          selInfo[1] = K_rem - gt;
        }
      }
    }
    __syncthreads();
    prefix |= ((uint32_t)selInfo[0]) << shift;
    K_rem = selInfo[1];
  }
  const uint32_t T = prefix;

  // --- compact candidates: keys > T, then ties == T (cap CAP) ---
  #pragma unroll
  for (int j = 0; j < 16; ++j) {
    if (key[j] > T) {
      int s = atomicAdd(&cnt, 1);
      cand[s] = ((j >> 2) << 10) + (t << 2) + (j & 3);
    }
  }
  __syncthreads();
  #pragma unroll
  for (int j = 0; j < 16; ++j) {
    if (key[j] == T) {
      int s = atomicAdd(&cnt, 1);
      if (s < CAP) cand[s] = ((j >> 2) << 10) + (t << 2) + (j & 3);
    }
  }
  __syncthreads();
  const int c = min(cnt, CAP);

  // --- exact fp32 rescore (arithmetic order identical to R1/R2) ---
  const float inv = invn[row];
  for (int ci = wid; ci < c; ci += 4) {
    int pidx = cand[ci];
    const f32x4* pr = reinterpret_cast<const f32x4*>(protos + (size_t)pidx * K_DIM);
    float s = 0.f;
    #pragma unroll
    for (int i = 0; i < 8; ++i) {
      f32x4 pv = pr[i * 64 + lane];
      f32x4 xv = lx[i * 64 + lane];
      s = fmaf(pv.x, xv.x, s);
      s = fmaf(pv.y, xv.y, s);
      s = fmaf(pv.z, xv.z, s);
      s = fmaf(pv.w, xv.w, s);
    }
    #pragma unroll
    for (int off = 1; off < 64; off <<= 1) s += __shfl_xor(s, off);
    if (lane == 0) cexact[ci] = s * inv;
  }
  __syncthreads();

  // --- exact top-16 + softmax (wave 0), publish (pos,val) pairs ---
  if (wid == 0) {
    float v = (lane < c) ? cexact[lane] : -3.0e38f;
    int pos = (lane < c) ? cand[lane] : 0x7fffffff;
    int rank = 0;
    for (int j = 0; j < c; ++j) {
      float vj = __shfl(v, j);
      int   pj = __shfl(pos, j);
      if (lane < c && j != lane)
        if (vj > v || (vj == v && pj < pos)) rank++;
    }
    bool sel = (lane < c) && (rank < TOPK);
    float vm = sel ? v : -3.0e38f;
    #pragma unroll
    for (int off = 1; off < 64; off <<= 1) vm = fmaxf(vm, __shfl_xor(vm, off));
    float e = sel ? expf((v - vm) * INV_T) : 0.f;
    float se = e;
    #pragma unroll
    for (int off = 1; off < 64; off <<= 1) se += __shfl_xor(se, off);
    unsigned long long bal = __ballot(sel);
    int slot = __popcll(bal & ((1ull << lane) - 1ull));
    if (sel) { spos[slot] = pos; sval[slot] = e / se; }
    if (lane == 0) csel = (int)__popcll(bal);
  }
  __syncthreads();

  // --- single streaming write: zeros with the selected values merged in ---
  const int ns = csel;
  f32x4* orow4w = reinterpret_cast<f32x4*>(orow);
  #pragma unroll
  for (int i = 0; i < 4; ++i) {
    f32x4 o = (f32x4){0.f, 0.f, 0.f, 0.f};
    for (int s = 0; s < ns; ++s) {
      int p = spos[s];
      if ((p >> 10) == i && ((p >> 2) & 255) == t) o[p & 3] = sval[s];
    }
    __builtin_nontemporal_store(o, orow4w + i * 256 + t);
  }
}

extern "C" void kernel_launch(void* const* d_in, const int* in_sizes, int n_in,
                              void* d_out, int out_size, void* d_ws, size_t ws_size,
                              hipStream_t stream) {
  const float* x = (const float*)d_in[0];
  const float* protos = (const float*)d_in[1];
  float* out = (float*)d_out;

  char* ws = (char*)d_ws;
  u16* xh = (u16*)ws;                                        // 64 MB
  u16* ph = (u16*)(ws + (size_t)M_ROWS * K_DIM * 2);         // 16 MB
  float* invn = (float*)(ws + (size_t)(M_ROWS + N_COLS) * K_DIM * 2); // 64 KB

  prep_x_kernel<<<M_ROWS, 256, 0, stream>>>(x, xh, invn);
  prep_p_kernel<<<N_COLS, 256, 0, stream>>>(protos, ph);

  dim3 gg(N_COLS / BN, M_ROWS / BM);
  gemm_bf16_kernel<<<gg, 256, 0, stream>>>(xh, ph, out);

  topk_kernel<<<M_ROWS, 256, 0, stream>>>(x, protos, invn, out);
}